// Round 1
// baseline (233.351 us; speedup 1.0000x reference)
//
#include <hip/hip_runtime.h>

#define RANK 32
#define DIM  128

// One wave (64 lanes) per output row. Lane l owns output dims {2l, 2l+1} and
// keeps its W2 column-pair slice (32 x float2 = 64 VGPRs) in registers for the
// whole kernel — this avoids 16KB of LDS reads per row (13 GB total, which
// would be LDS-BW-bound at ~250us, worse than the ~80us HBM floor).
__global__ __launch_bounds__(256, 4) void lowrank_emb_kernel(
    const int* __restrict__ idx,
    const float* __restrict__ W1,
    const float* __restrict__ W2,
    float* __restrict__ out,
    int n_rows)
{
  const int lane         = threadIdx.x & 63;
  const int waveInBlock  = threadIdx.x >> 6;
  const int wavesPerBlk  = blockDim.x >> 6;
  const int globalWave   = blockIdx.x * wavesPerBlk + waveInBlock;
  const int totalWaves   = gridDim.x * wavesPerBlk;

  // Per-lane W2 slice: w2r[k] = W2[k][2*lane .. 2*lane+1]
  const int d = lane * 2;
  float2 w2r[RANK];
  #pragma unroll
  for (int k = 0; k < RANK; ++k) {
    w2r[k] = *reinterpret_cast<const float2*>(&W2[k * DIM + d]);
  }

  for (int row = globalWave; row < n_rows; row += totalWaves) {
    // idx[row] is wave-uniform; force it into an SGPR so the W1-row loads
    // become scalar (or at least same-address broadcast) loads.
    int e = __builtin_amdgcn_readfirstlane(idx[row]);
    const float* __restrict__ w1p = W1 + (size_t)e * RANK;

    float a0 = 0.f, a1 = 0.f;
    #pragma unroll
    for (int k = 0; k < RANK; ++k) {
      float w = w1p[k];              // uniform (SGPR-addressed) load
      a0 = fmaf(w, w2r[k].x, a0);    // v_fmac_f32 with one SGPR operand
      a1 = fmaf(w, w2r[k].y, a1);
    }

    float2 r = make_float2(a0, a1);
    *reinterpret_cast<float2*>(&out[(size_t)row * DIM + d]) = r;  // 512B/wave coalesced
  }
}

extern "C" void kernel_launch(void* const* d_in, const int* in_sizes, int n_in,
                              void* d_out, int out_size, void* d_ws, size_t ws_size,
                              hipStream_t stream) {
  const int*   idx = (const int*)d_in[0];   // [4096*200] indices
  const float* W1  = (const float*)d_in[1]; // [1e6, 32]
  const float* W2  = (const float*)d_in[2]; // [32, 128]
  float*       out = (float*)d_out;         // [4096*200, 128]
  const int n_rows = in_sizes[0];

  const int threads = 256;                  // 4 waves/block
  const int blocks  = 2048;                 // grid-stride; 8 blocks/CU worth of waves
  hipLaunchKernelGGL(lowrank_emb_kernel, dim3(blocks), dim3(threads), 0, stream,
                     idx, W1, W2, out, n_rows);
}

// Round 2
// 212.941 us; speedup vs baseline: 1.0958x; 1.0958x over previous
//
#include <hip/hip_runtime.h>

#define RANK 32
#define DIM  128

// One wave per 2 output rows. Lane l owns output dims {2l, 2l+1} and keeps its
// W2 column-pair slice (32 x float2 = 64 VGPRs) PINNED in registers (opaque asm
// below). W1 rows travel through the scalar path (readfirstlane'd row index ->
// uniform address -> s_load into SGPRs; round-1 SGPR_Count=80 confirmed this).
// Processing 2 rows/iteration gives two independent SMEM latency chains per
// loop body to hide the ~600-900cy gather latency.
__global__ __launch_bounds__(256, 4) void lowrank_emb_kernel(
    const int* __restrict__ idx,
    const float* __restrict__ W1,
    const float* __restrict__ W2,
    float* __restrict__ out,
    int n_rows)
{
  const int lane        = threadIdx.x & 63;
  const int waveInBlock = threadIdx.x >> 6;
  const int wavesPerBlk = blockDim.x >> 6;
  const int globalWave  = blockIdx.x * wavesPerBlk + waveInBlock;
  const int totalWaves  = gridDim.x * wavesPerBlk;

  const int d = lane * 2;
  float2 w2r[RANK];
  #pragma unroll
  for (int k = 0; k < RANK; ++k)
    w2r[k] = *reinterpret_cast<const float2*>(&W2[k * DIM + d]);
  // Pin the W2 slice in VGPRs. Round-1 kernel had VGPR_Count=36: the compiler
  // sank these loads into the row loop, putting an L1 round-trip in every
  // iteration's critical path. Opaque asm outputs cannot be rematerialized,
  // so the values must stay register-resident.
  #pragma unroll
  for (int k = 0; k < RANK; ++k)
    asm("" : "+v"(w2r[k].x), "+v"(w2r[k].y));

  const int nChunks = n_rows >> 1;
  for (int c = globalWave; c < nChunks; c += totalWaves) {
    const int row = c << 1;
    // Both indices in one wave-uniform 8B load.
    int2 ip = *reinterpret_cast<const int2*>(&idx[row]);
    const int e0 = __builtin_amdgcn_readfirstlane(ip.x);
    const int e1 = __builtin_amdgcn_readfirstlane(ip.y);
    const float* __restrict__ p0 = W1 + (size_t)e0 * RANK;
    const float* __restrict__ p1 = W1 + (size_t)e1 * RANK;

    float a00 = 0.f, a01 = 0.f, a10 = 0.f, a11 = 0.f;
    #pragma unroll
    for (int k = 0; k < RANK; ++k) {
      const float w0 = p0[k];   // uniform -> SGPR (s_load_dwordx*)
      const float w1v = p1[k];
      a00 = fmaf(w0,  w2r[k].x, a00);
      a01 = fmaf(w0,  w2r[k].y, a01);
      a10 = fmaf(w1v, w2r[k].x, a10);
      a11 = fmaf(w1v, w2r[k].y, a11);
    }
    // Two coalesced 512B wave-stores, 1KB contiguous per iteration.
    *reinterpret_cast<float2*>(&out[(size_t)row * DIM + d])       = make_float2(a00, a01);
    *reinterpret_cast<float2*>(&out[(size_t)(row + 1) * DIM + d]) = make_float2(a10, a11);
  }

  // Tail for odd n_rows (not hit at 819200, kept for correctness).
  if ((n_rows & 1) && globalWave == 0) {
    const int row = n_rows - 1;
    const int e = __builtin_amdgcn_readfirstlane(idx[row]);
    const float* __restrict__ p = W1 + (size_t)e * RANK;
    float a0 = 0.f, a1 = 0.f;
    #pragma unroll
    for (int k = 0; k < RANK; ++k) {
      const float w = p[k];
      a0 = fmaf(w, w2r[k].x, a0);
      a1 = fmaf(w, w2r[k].y, a1);
    }
    *reinterpret_cast<float2*>(&out[(size_t)row * DIM + d]) = make_float2(a0, a1);
  }
}

extern "C" void kernel_launch(void* const* d_in, const int* in_sizes, int n_in,
                              void* d_out, int out_size, void* d_ws, size_t ws_size,
                              hipStream_t stream) {
  const int*   idx = (const int*)d_in[0];   // [4096*200]
  const float* W1  = (const float*)d_in[1]; // [1e6, 32]
  const float* W2  = (const float*)d_in[2]; // [32, 128]
  float*       out = (float*)d_out;         // [4096*200, 128]
  const int n_rows = in_sizes[0];

  const int threads = 256;   // 4 waves/block
  const int blocks  = 2048;  // 8192 waves grid-striding 409600 chunks
  hipLaunchKernelGGL(lowrank_emb_kernel, dim3(blocks), dim3(threads), 0, stream,
                     idx, W1, W2, out, n_rows);
}